// Round 1
// baseline (1014.554 us; speedup 1.0000x reference)
//
#include <hip/hip_runtime.h>
#include <hip/hip_bf16.h>
#include <math.h>

#define VNUM 100000
#define DIM 64
#define NEDGE 1000000
#define EPS 1e-7f

// ---------------------------------------------------------------------------
// Phase 1: edge gather + scale + scatter-add (atomic) into ptr[V][64] (d_ws)
// 16 threads per edge, float4 per thread.
// ---------------------------------------------------------------------------
__global__ __launch_bounds__(256) void edge_scatter_kernel(
    const int* __restrict__ eidx,     // [2, NEDGE] (int32 from harness)
    const float* __restrict__ enorm,  // [NEDGE]
    const float* __restrict__ esgn,   // [NEDGE]
    const float* __restrict__ vrepr,  // [VNUM, 64]
    float* __restrict__ ptr)          // [VNUM, 64] accumulator (pre-zeroed)
{
    long gid = (long)blockIdx.x * blockDim.x + threadIdx.x;
    int e = (int)(gid >> 4);
    int q = (int)(gid & 15);
    if (e >= NEDGE) return;

    int s = eidx[e];
    int t = eidx[NEDGE + e];
    float w = esgn[e] * enorm[e];

    const float4 vv = *reinterpret_cast<const float4*>(vrepr + (long)s * DIM + q * 4);
    float* dst = ptr + (long)t * DIM + q * 4;
    atomicAdd(dst + 0, vv.x * w);
    atomicAdd(dst + 1, vv.y * w);
    atomicAdd(dst + 2, vv.z * w);
    atomicAdd(dst + 3, vv.w * w);
}

// ---------------------------------------------------------------------------
// Phase 2: dual head GEMM + bias + softplus, fused.
//   loc[v][j] = sum_d ptr[v][d] * W_loc[d][j] + b_loc[j]
//   std[v][j] = softplus(sum_d ptr[v][d] * W_std[d][j] + b_std[j]) + EPS
// Block = 256 threads = 4 rows x 64 cols. W_loc/W_std staged in LDS
// (lane reads stride-1 -> 2 lanes/bank -> conflict-free). Row value
// broadcast from LDS (wave-uniform address -> broadcast, free).
// ---------------------------------------------------------------------------
__global__ __launch_bounds__(256) void head_kernel(
    const float* __restrict__ ptr,    // [VNUM, 64]
    const float* __restrict__ W_loc,  // [64, 64]
    const float* __restrict__ b_loc,  // [64]
    const float* __restrict__ W_std,  // [64, 64]
    const float* __restrict__ b_std,  // [64]
    float* __restrict__ out)          // [2, VNUM, 64] : loc then std
{
    __shared__ float Wl[DIM * DIM];   // 16 KiB
    __shared__ float Ws[DIM * DIM];   // 16 KiB
    __shared__ float rows[4][DIM];    // 1 KiB

    const int tid  = threadIdx.x;
    const int j    = tid & 63;        // output column (lane)
    const int rsub = tid >> 6;        // which of the 4 rows (wave-uniform)

    for (int i = tid; i < DIM * DIM; i += 256) {
        Wl[i] = W_loc[i];
        Ws[i] = W_std[i];
    }
    const float blj = b_loc[j];
    const float bsj = b_std[j];
    __syncthreads();

    for (int vbase = blockIdx.x * 4; vbase < VNUM; vbase += gridDim.x * 4) {
        const int v = vbase + rsub;
        rows[rsub][j] = (v < VNUM) ? ptr[(long)v * DIM + j] : 0.0f;
        __syncthreads();

        float accl = 0.0f, accs = 0.0f;
        #pragma unroll
        for (int d = 0; d < DIM; ++d) {
            const float pd = rows[rsub][d];   // wave-uniform -> LDS broadcast
            accl = fmaf(pd, Wl[d * DIM + j], accl);
            accs = fmaf(pd, Ws[d * DIM + j], accs);
        }

        if (v < VNUM) {
            out[(long)v * DIM + j] = accl + blj;
            const float x = accs + bsj;
            // jax.nn.softplus(x) = max(x,0) + log1p(exp(-|x|))
            const float sp = fmaxf(x, 0.0f) + log1pf(expf(-fabsf(x)));
            out[(long)VNUM * DIM + (long)v * DIM + j] = sp + EPS;
        }
        __syncthreads();
    }
}

extern "C" void kernel_launch(void* const* d_in, const int* in_sizes, int n_in,
                              void* d_out, int out_size, void* d_ws, size_t ws_size,
                              hipStream_t stream) {
    const int*   eidx  = (const int*)d_in[0];
    const float* enorm = (const float*)d_in[1];
    const float* esgn  = (const float*)d_in[2];
    const float* vrepr = (const float*)d_in[3];
    const float* W_loc = (const float*)d_in[4];
    const float* b_loc = (const float*)d_in[5];
    const float* W_std = (const float*)d_in[6];
    const float* b_std = (const float*)d_in[7];
    float* out = (float*)d_out;

    float* ptr = (float*)d_ws;  // [VNUM, DIM] accumulator

    // Phase 0: zero the accumulator (ws is re-poisoned to 0xAA each call).
    hipMemsetAsync(ptr, 0, (size_t)VNUM * DIM * sizeof(float), stream);

    // Phase 1: edge scatter. 16 threads/edge.
    {
        const long total = (long)NEDGE * 16;
        const int block = 256;
        const int grid = (int)((total + block - 1) / block);  // 62500
        edge_scatter_kernel<<<grid, block, 0, stream>>>(eidx, enorm, esgn, vrepr, ptr);
    }

    // Phase 2: fused dual-head GEMM + softplus.
    {
        const int block = 256;
        const int grid = 2048;  // grid-stride over 25000 row-groups
        head_kernel<<<grid, block, 0, stream>>>(ptr, W_loc, b_loc, W_std, b_std, out);
    }
}

// Round 3
// 683.226 us; speedup vs baseline: 1.4849x; 1.4849x over previous
//
#include <hip/hip_runtime.h>
#include <hip/hip_bf16.h>
#include <math.h>

#define VNUM 100000
#define DIM 64
#define NEDGE 1000000
#define EPS 1e-7f

#define NBIN 256
#define ROWS_PER_BIN 391          // ceil(100000/256)
#define QCAP 6144
#define THREADS 1024

// ---------------------------------------------------------------------------
// Owner-computes segment sum: block b owns rows [b*391, b*391+391).
// Phase A: scan all edge targets (L2-multicast), enqueue matches to LDS.
// Phase B: 16 waves drain queue; coalesced vrepr gather + LDS atomic add.
// No global atomics except a (practically never taken) overflow fallback.
// ---------------------------------------------------------------------------
__global__ __launch_bounds__(THREADS, 1) void binned_scatter_kernel(
    const int* __restrict__ eidx,     // [2, NEDGE]
    const float* __restrict__ enorm,  // [NEDGE]
    const float* __restrict__ esgn,   // [NEDGE]
    const float* __restrict__ vrepr,  // [VNUM, 64]
    float* __restrict__ ptr)          // [VNUM, 64] (pre-zeroed)
{
    __shared__ float acc[ROWS_PER_BIN * DIM];   // 100,096 B
    __shared__ unsigned int qmeta[QCAP];        // s | (t_local<<17)
    __shared__ float qw[QCAP];                  // esgn*enorm
    __shared__ int qtail;

    const int tid = threadIdx.x;
    const int b   = blockIdx.x;
    const int lo  = b * ROWS_PER_BIN;
    const int hi  = (lo + ROWS_PER_BIN < VNUM) ? lo + ROWS_PER_BIN : VNUM;

    for (int i = tid; i < ROWS_PER_BIN * DIM; i += THREADS) acc[i] = 0.0f;
    if (tid == 0) qtail = 0;
    __syncthreads();

    // ---- Phase A: scan targets, enqueue matches -------------------------
    const int4* t4 = reinterpret_cast<const int4*>(eidx + NEDGE);
    for (int i = tid; i < NEDGE / 4; i += THREADS) {
        const int4 tt = t4[i];
        const int base_e = i * 4;
        #pragma unroll
        for (int k = 0; k < 4; ++k) {
            const int t = (k == 0) ? tt.x : (k == 1) ? tt.y : (k == 2) ? tt.z : tt.w;
            if (t >= lo && t < hi) {
                const int e = base_e + k;
                const int s = eidx[e];
                const float w = esgn[e] * enorm[e];
                const int pos = atomicAdd(&qtail, 1);
                if (pos < QCAP) {
                    qmeta[pos] = (unsigned)s | ((unsigned)(t - lo) << 17);
                    qw[pos] = w;
                } else {
                    // overflow fallback: correct, ~never taken
                    const float* src = vrepr + (long)s * DIM;
                    float* dst = ptr + (long)t * DIM;
                    for (int j = 0; j < DIM; ++j) atomicAdd(dst + j, src[j] * w);
                }
            }
        }
    }
    __syncthreads();

    int n = qtail; if (n > QCAP) n = QCAP;

    // ---- Phase B: drain queue, 1 edge per wave, 2-deep pipelined --------
    const int lane = tid & 63;
    const int wid  = tid >> 6;     // 16 waves
    int i = wid;
    for (; i + 16 < n; i += 32) {
        const unsigned m0 = qmeta[i];
        const unsigned m1 = qmeta[i + 16];
        const float w0 = qw[i];
        const float w1 = qw[i + 16];
        const float v0 = vrepr[(long)(m0 & 0x1FFFF) * DIM + lane];
        const float v1 = vrepr[(long)(m1 & 0x1FFFF) * DIM + lane];
        atomicAdd(&acc[(m0 >> 17) * DIM + lane], v0 * w0);
        atomicAdd(&acc[(m1 >> 17) * DIM + lane], v1 * w1);
    }
    if (i < n) {
        const unsigned m0 = qmeta[i];
        const float w0 = qw[i];
        const float v0 = vrepr[(long)(m0 & 0x1FFFF) * DIM + lane];
        atomicAdd(&acc[(m0 >> 17) * DIM + lane], v0 * w0);
    }
    __syncthreads();

    // ---- Writeout (adds ptr to pick up any fallback atomics) ------------
    const int nrows = hi - lo;
    for (int idx = tid; idx < nrows * DIM; idx += THREADS) {
        const long g = (long)lo * DIM + idx;
        ptr[g] = acc[idx] + ptr[g];
    }
}

// ---------------------------------------------------------------------------
// Dual head GEMM + bias + softplus (unchanged from R1).
// ---------------------------------------------------------------------------
__global__ __launch_bounds__(256) void head_kernel(
    const float* __restrict__ ptr,
    const float* __restrict__ W_loc,
    const float* __restrict__ b_loc,
    const float* __restrict__ W_std,
    const float* __restrict__ b_std,
    float* __restrict__ out)
{
    __shared__ float Wl[DIM * DIM];
    __shared__ float Ws[DIM * DIM];
    __shared__ float rows[4][DIM];

    const int tid  = threadIdx.x;
    const int j    = tid & 63;
    const int rsub = tid >> 6;

    for (int i = tid; i < DIM * DIM; i += 256) {
        Wl[i] = W_loc[i];
        Ws[i] = W_std[i];
    }
    const float blj = b_loc[j];
    const float bsj = b_std[j];
    __syncthreads();

    for (int vbase = blockIdx.x * 4; vbase < VNUM; vbase += gridDim.x * 4) {
        const int v = vbase + rsub;
        rows[rsub][j] = (v < VNUM) ? ptr[(long)v * DIM + j] : 0.0f;
        __syncthreads();

        float accl = 0.0f, accs = 0.0f;
        #pragma unroll
        for (int d = 0; d < DIM; ++d) {
            const float pd = rows[rsub][d];
            accl = fmaf(pd, Wl[d * DIM + j], accl);
            accs = fmaf(pd, Ws[d * DIM + j], accs);
        }

        if (v < VNUM) {
            out[(long)v * DIM + j] = accl + blj;
            const float x = accs + bsj;
            const float sp = fmaxf(x, 0.0f) + log1pf(expf(-fabsf(x)));
            out[(long)VNUM * DIM + (long)v * DIM + j] = sp + EPS;
        }
        __syncthreads();
    }
}

extern "C" void kernel_launch(void* const* d_in, const int* in_sizes, int n_in,
                              void* d_out, int out_size, void* d_ws, size_t ws_size,
                              hipStream_t stream) {
    const int*   eidx  = (const int*)d_in[0];
    const float* enorm = (const float*)d_in[1];
    const float* esgn  = (const float*)d_in[2];
    const float* vrepr = (const float*)d_in[3];
    const float* W_loc = (const float*)d_in[4];
    const float* b_loc = (const float*)d_in[5];
    const float* W_std = (const float*)d_in[6];
    const float* b_std = (const float*)d_in[7];
    float* out = (float*)d_out;

    float* ptr = (float*)d_ws;  // [VNUM, DIM] accumulator

    // Zero the accumulator (needed for the overflow-fallback path).
    hipMemsetAsync(ptr, 0, (size_t)VNUM * DIM * sizeof(float), stream);

    // Owner-computes binned segment sum: 256 blocks, 1 per CU.
    binned_scatter_kernel<<<NBIN, THREADS, 0, stream>>>(eidx, enorm, esgn, vrepr, ptr);

    // Fused dual-head GEMM + softplus.
    head_kernel<<<2048, 256, 0, stream>>>(ptr, W_loc, b_loc, W_std, b_std, out);
}

// Round 4
// 652.653 us; speedup vs baseline: 1.5545x; 1.0468x over previous
//
#include <hip/hip_runtime.h>
#include <hip/hip_bf16.h>
#include <math.h>

#define VNUM 100000
#define DIM 64
#define NEDGE 1000000
#define EPS 1e-7f

#define NBIN 256
#define ROWS_PER_BIN 391          // ceil(100000/256); bin = t/391 fits [0,255]
#define NREP 8                    // replica counters per bin (contention /8)
#define SUBCAP 1024               // records per (bin,replica); mean 488, +25 sigma
#define OVF_CAP 65536

// d_ws layout:
//   [0,      8192) : cnt[NBIN*NREP]  (u32)     -- memset 0 each call
//   [8192,   8196) : ovf_cnt (u32)             -- covered by same memset
//   [16384,  +16 MiB) : bucket[NBIN*NREP*SUBCAP] uint2 {meta, w_bits}
//   then           : ovf[OVF_CAP*3] u32 {meta, bin, w_bits}
// total ~17.6 MB (ws proved >= 25.6 MB in R1/R3).

// ---------------------------------------------------------------------------
// Kernel 1: one pass over edges -> bucket records by target bin.
// meta = s (17b) | t_local (9b) << 17.
// ---------------------------------------------------------------------------
__global__ __launch_bounds__(256) void bucket_kernel(
    const int* __restrict__ eidx,     // [2, NEDGE]
    const float* __restrict__ enorm,  // [NEDGE]
    const float* __restrict__ esgn,   // [NEDGE]
    unsigned* __restrict__ cnt,
    unsigned* __restrict__ ovf_cnt,
    uint2* __restrict__ bucket,
    unsigned* __restrict__ ovf)
{
    const int e = blockIdx.x * 256 + threadIdx.x;
    if (e >= NEDGE) return;

    const int s = eidx[e];
    const int t = eidx[NEDGE + e];
    const float w = esgn[e] * enorm[e];

    const int bin = t / ROWS_PER_BIN;              // magic-mul, compile-time const
    const int tl  = t - bin * ROWS_PER_BIN;
    const unsigned meta = (unsigned)s | ((unsigned)tl << 17);
    const int rep = (blockIdx.x ^ (threadIdx.x >> 6)) & (NREP - 1);

    const unsigned slot = atomicAdd(&cnt[bin * NREP + rep], 1u);
    if (slot < SUBCAP) {
        bucket[(unsigned)(bin * NREP + rep) * SUBCAP + slot] =
            make_uint2(meta, __float_as_uint(w));
    } else {
        const unsigned o = atomicAdd(ovf_cnt, 1u);
        if (o < OVF_CAP) {
            ovf[o * 3 + 0] = meta;
            ovf[o * 3 + 1] = (unsigned)bin;
            ovf[o * 3 + 2] = __float_as_uint(w);
        }
    }
}

// ---------------------------------------------------------------------------
// Kernel 2: block b = bin b. Drain bucket lists into LDS accumulator
// (wave-per-edge coalesced gather, conflict-free ds_add), then fused dual
// head GEMM + softplus straight from LDS. No ptr buffer, no second pass.
// ---------------------------------------------------------------------------
__global__ __launch_bounds__(1024, 1) void accum_head_kernel(
    const float* __restrict__ vrepr,  // [VNUM, 64]
    const float* __restrict__ W_loc, const float* __restrict__ b_loc,
    const float* __restrict__ W_std, const float* __restrict__ b_std,
    const unsigned* __restrict__ cnt, const unsigned* __restrict__ ovf_cnt,
    const uint2* __restrict__ bucket, const unsigned* __restrict__ ovf,
    float* __restrict__ out)          // [2, VNUM, 64]
{
    __shared__ float acc[ROWS_PER_BIN * DIM];   // 100,096 B
    __shared__ float Wl[DIM * DIM];             // 16 KiB
    __shared__ float Ws[DIM * DIM];             // 16 KiB
    __shared__ uint2 stage[SUBCAP];             // 8 KiB   (total ~141 KiB)

    const int tid  = threadIdx.x;
    const int b    = blockIdx.x;
    const int lane = tid & 63;
    const int wid  = tid >> 6;                  // 16 waves
    const int lo   = b * ROWS_PER_BIN;
    const int nrows = (VNUM - lo < ROWS_PER_BIN) ? (VNUM - lo) : ROWS_PER_BIN;

    for (int i = tid; i < ROWS_PER_BIN * DIM; i += 1024) acc[i] = 0.0f;
    for (int i = tid; i < DIM * DIM; i += 1024) { Wl[i] = W_loc[i]; Ws[i] = W_std[i]; }
    __syncthreads();

    // ---- drain the 8 replica lists ----
    for (int rep = 0; rep < NREP; ++rep) {
        int n = (int)cnt[b * NREP + rep];
        if (n > SUBCAP) n = SUBCAP;
        const uint2* src = bucket + (unsigned)(b * NREP + rep) * SUBCAP;
        for (int i = tid; i < n; i += 1024) stage[i] = src[i];   // coalesced
        __syncthreads();

        int i = wid;
        for (; i + 16 < n; i += 32) {           // 2-deep pipelined, wave-per-edge
            const uint2 r0 = stage[i];
            const uint2 r1 = stage[i + 16];
            const float v0 = vrepr[(long)(r0.x & 0x1FFFF) * DIM + lane];
            const float v1 = vrepr[(long)(r1.x & 0x1FFFF) * DIM + lane];
            atomicAdd(&acc[(r0.x >> 17) * DIM + lane], v0 * __uint_as_float(r0.y));
            atomicAdd(&acc[(r1.x >> 17) * DIM + lane], v1 * __uint_as_float(r1.y));
        }
        if (i < n) {
            const uint2 r0 = stage[i];
            const float v0 = vrepr[(long)(r0.x & 0x1FFFF) * DIM + lane];
            atomicAdd(&acc[(r0.x >> 17) * DIM + lane], v0 * __uint_as_float(r0.y));
        }
        __syncthreads();                        // protect stage[] reuse
    }

    // ---- overflow entries (normally zero) ----
    int nov = (int)*ovf_cnt;
    if (nov > OVF_CAP) nov = OVF_CAP;
    for (int i = wid; i < nov; i += 16) {
        const unsigned meta = ovf[i * 3 + 0];
        const unsigned obin = ovf[i * 3 + 1];
        const float    w    = __uint_as_float(ovf[i * 3 + 2]);
        if ((int)obin == b) {
            const float v = vrepr[(long)(meta & 0x1FFFF) * DIM + lane];
            atomicAdd(&acc[(meta >> 17) * DIM + lane], v * w);
        }
    }
    __syncthreads();

    // ---- fused dual head GEMM + bias + softplus, straight from LDS ----
    const float blj = b_loc[lane];
    const float bsj = b_std[lane];
    for (int r = wid; r < nrows; r += 16) {
        float al = 0.0f, as_ = 0.0f;
        #pragma unroll
        for (int d = 0; d < DIM; ++d) {
            const float pd = acc[r * DIM + d];          // wave-uniform broadcast
            al  = fmaf(pd, Wl[d * DIM + lane], al);     // stride-1, conflict-free
            as_ = fmaf(pd, Ws[d * DIM + lane], as_);
        }
        const long v = lo + r;
        out[v * DIM + lane] = al + blj;
        const float x = as_ + bsj;
        const float sp = fmaxf(x, 0.0f) + log1pf(expf(-fabsf(x)));  // jax softplus
        out[(long)VNUM * DIM + v * DIM + lane] = sp + EPS;
    }
}

extern "C" void kernel_launch(void* const* d_in, const int* in_sizes, int n_in,
                              void* d_out, int out_size, void* d_ws, size_t ws_size,
                              hipStream_t stream) {
    const int*   eidx  = (const int*)d_in[0];
    const float* enorm = (const float*)d_in[1];
    const float* esgn  = (const float*)d_in[2];
    const float* vrepr = (const float*)d_in[3];
    const float* W_loc = (const float*)d_in[4];
    const float* b_loc = (const float*)d_in[5];
    const float* W_std = (const float*)d_in[6];
    const float* b_std = (const float*)d_in[7];
    float* out = (float*)d_out;

    unsigned* cnt     = (unsigned*)d_ws;
    unsigned* ovf_cnt = (unsigned*)((char*)d_ws + 8192);
    uint2*    bucket  = (uint2*)((char*)d_ws + 16384);
    unsigned* ovf     = (unsigned*)((char*)d_ws + 16384 +
                                    (size_t)NBIN * NREP * SUBCAP * sizeof(uint2));

    // zero counters + overflow count (one small memset)
    hipMemsetAsync(d_ws, 0, 16384, stream);

    // one pass: bucket edges by target bin
    bucket_kernel<<<(NEDGE + 255) / 256, 256, 0, stream>>>(
        eidx, enorm, esgn, cnt, ovf_cnt, bucket, ovf);

    // one block per bin: accumulate + fused heads
    accum_head_kernel<<<NBIN, 1024, 0, stream>>>(
        vrepr, W_loc, b_loc, W_std, b_std, cnt, ovf_cnt, bucket, ovf, out);
}

// Round 5
// 561.097 us; speedup vs baseline: 1.8082x; 1.1632x over previous
//
#include <hip/hip_runtime.h>
#include <hip/hip_bf16.h>
#include <math.h>

#define VNUM 100000
#define DIM 64
#define NEDGE 1000000
#define EPS 1e-7f

#define NBIN 256
#define ROWS_PER_BIN 391          // ceil(100000/256); bin = t/391 fits [0,255]
#define NREP 8                    // replica lists per bin
#define SUBCAP 1024               // records per (bin,replica); mean 488 (+24 sigma)
#define OVF_CAP 65536
#define CNT_STRIDE 32             // one counter per 128B line (atomic same-line serialization fix)

// d_ws layout:
//   [0, 256K)        : cnt[NBIN*NREP] padded to CNT_STRIDE u32 each
//   [256K, +4)       : ovf_cnt
//   [1M, +16M)       : bucket[NBIN*NREP*SUBCAP] uint2 {meta, w_bits}
//   [17M, +768K)     : ovf[OVF_CAP*3]
// memset [0, 512K) each call.

// ---------------------------------------------------------------------------
// Kernel 1: one pass over edges -> bucket records by target bin.
// meta = s (17b) | t_local (9b) << 17.
// ---------------------------------------------------------------------------
__global__ __launch_bounds__(256) void bucket_kernel(
    const int* __restrict__ eidx,     // [2, NEDGE]
    const float* __restrict__ enorm,  // [NEDGE]
    const float* __restrict__ esgn,   // [NEDGE]
    unsigned* __restrict__ cnt,       // padded: cnt[(bin*NREP+rep)*CNT_STRIDE]
    unsigned* __restrict__ ovf_cnt,
    uint2* __restrict__ bucket,
    unsigned* __restrict__ ovf)
{
    const int e = blockIdx.x * 256 + threadIdx.x;
    if (e >= NEDGE) return;

    const int s = eidx[e];
    const int t = eidx[NEDGE + e];
    const float w = esgn[e] * enorm[e];

    const int bin = t / ROWS_PER_BIN;              // magic-mul
    const int tl  = t - bin * ROWS_PER_BIN;
    const unsigned meta = (unsigned)s | ((unsigned)tl << 17);
    const int rep = (blockIdx.x + (threadIdx.x >> 6)) & (NREP - 1);

    const unsigned slot = atomicAdd(&cnt[(bin * NREP + rep) * CNT_STRIDE], 1u);
    if (slot < SUBCAP) {
        bucket[(unsigned)(bin * NREP + rep) * SUBCAP + slot] =
            make_uint2(meta, __float_as_uint(w));
    } else {
        const unsigned o = atomicAdd(ovf_cnt, 1u);
        if (o < OVF_CAP) {
            ovf[o * 3 + 0] = meta;
            ovf[o * 3 + 1] = (unsigned)bin;
            ovf[o * 3 + 2] = __float_as_uint(w);
        }
    }
}

// ---------------------------------------------------------------------------
// Kernel 2: block b = bin b. Drain bucket lists into LDS accumulator with
// 8-deep wave-level gather pipelining (128 outstanding 256B loads per CU),
// then fused dual head GEMM + softplus straight from LDS.
// ---------------------------------------------------------------------------
__global__ __launch_bounds__(1024, 1) void accum_head_kernel(
    const float* __restrict__ vrepr,  // [VNUM, 64]
    const float* __restrict__ W_loc, const float* __restrict__ b_loc,
    const float* __restrict__ W_std, const float* __restrict__ b_std,
    const unsigned* __restrict__ cnt, const unsigned* __restrict__ ovf_cnt,
    const uint2* __restrict__ bucket, const unsigned* __restrict__ ovf,
    float* __restrict__ out)          // [2, VNUM, 64]
{
    __shared__ float acc[ROWS_PER_BIN * DIM];   // 100,096 B
    __shared__ float Wl[DIM * DIM];             // 16 KiB
    __shared__ float Ws[DIM * DIM];             // 16 KiB
    __shared__ uint2 stage[SUBCAP];             // 8 KiB   (total ~141 KiB)

    const int tid  = threadIdx.x;
    const int b    = blockIdx.x;
    const int lane = tid & 63;
    const int wid  = tid >> 6;                  // 16 waves
    const int lo   = b * ROWS_PER_BIN;
    const int nrows = (VNUM - lo < ROWS_PER_BIN) ? (VNUM - lo) : ROWS_PER_BIN;

    for (int i = tid; i < ROWS_PER_BIN * DIM; i += 1024) acc[i] = 0.0f;
    for (int i = tid; i < DIM * DIM; i += 1024) { Wl[i] = W_loc[i]; Ws[i] = W_std[i]; }
    __syncthreads();

    // ---- drain the 8 replica lists ----
    for (int rep = 0; rep < NREP; ++rep) {
        int n = (int)cnt[(b * NREP + rep) * CNT_STRIDE];
        if (n > SUBCAP) n = SUBCAP;
        const uint2* src = bucket + (unsigned)(b * NREP + rep) * SUBCAP;
        for (int i = tid; i < n; i += 1024) stage[i] = src[i];   // coalesced
        __syncthreads();

        int i = wid;
        // 8-deep pipelined: 8 independent gathers in flight per wave.
        for (; i + 112 < n; i += 128) {
            uint2 r0 = stage[i +   0], r1 = stage[i +  16];
            uint2 r2 = stage[i +  32], r3 = stage[i +  48];
            uint2 r4 = stage[i +  64], r5 = stage[i +  80];
            uint2 r6 = stage[i +  96], r7 = stage[i + 112];
            float v0 = vrepr[(long)(r0.x & 0x1FFFF) * DIM + lane];
            float v1 = vrepr[(long)(r1.x & 0x1FFFF) * DIM + lane];
            float v2 = vrepr[(long)(r2.x & 0x1FFFF) * DIM + lane];
            float v3 = vrepr[(long)(r3.x & 0x1FFFF) * DIM + lane];
            float v4 = vrepr[(long)(r4.x & 0x1FFFF) * DIM + lane];
            float v5 = vrepr[(long)(r5.x & 0x1FFFF) * DIM + lane];
            float v6 = vrepr[(long)(r6.x & 0x1FFFF) * DIM + lane];
            float v7 = vrepr[(long)(r7.x & 0x1FFFF) * DIM + lane];
            atomicAdd(&acc[(r0.x >> 17) * DIM + lane], v0 * __uint_as_float(r0.y));
            atomicAdd(&acc[(r1.x >> 17) * DIM + lane], v1 * __uint_as_float(r1.y));
            atomicAdd(&acc[(r2.x >> 17) * DIM + lane], v2 * __uint_as_float(r2.y));
            atomicAdd(&acc[(r3.x >> 17) * DIM + lane], v3 * __uint_as_float(r3.y));
            atomicAdd(&acc[(r4.x >> 17) * DIM + lane], v4 * __uint_as_float(r4.y));
            atomicAdd(&acc[(r5.x >> 17) * DIM + lane], v5 * __uint_as_float(r5.y));
            atomicAdd(&acc[(r6.x >> 17) * DIM + lane], v6 * __uint_as_float(r6.y));
            atomicAdd(&acc[(r7.x >> 17) * DIM + lane], v7 * __uint_as_float(r7.y));
        }
        for (; i < n; i += 16) {
            const uint2 r = stage[i];
            const float v = vrepr[(long)(r.x & 0x1FFFF) * DIM + lane];
            atomicAdd(&acc[(r.x >> 17) * DIM + lane], v * __uint_as_float(r.y));
        }
        __syncthreads();                        // protect stage[] reuse
    }

    // ---- overflow entries (normally zero) ----
    int nov = (int)*ovf_cnt;
    if (nov > OVF_CAP) nov = OVF_CAP;
    for (int i = wid; i < nov; i += 16) {
        const unsigned meta = ovf[i * 3 + 0];
        const unsigned obin = ovf[i * 3 + 1];
        const float    w    = __uint_as_float(ovf[i * 3 + 2]);
        if ((int)obin == b) {
            const float v = vrepr[(long)(meta & 0x1FFFF) * DIM + lane];
            atomicAdd(&acc[(meta >> 17) * DIM + lane], v * w);
        }
    }
    __syncthreads();

    // ---- fused dual head GEMM + bias + softplus, straight from LDS ----
    const float blj = b_loc[lane];
    const float bsj = b_std[lane];
    for (int r = wid; r < nrows; r += 16) {
        float al = 0.0f, as_ = 0.0f;
        #pragma unroll
        for (int d = 0; d < DIM; ++d) {
            const float pd = acc[r * DIM + d];          // wave-uniform broadcast
            al  = fmaf(pd, Wl[d * DIM + lane], al);     // stride-1, conflict-free
            as_ = fmaf(pd, Ws[d * DIM + lane], as_);
        }
        const long v = lo + r;
        out[v * DIM + lane] = al + blj;
        const float x = as_ + bsj;
        const float sp = fmaxf(x, 0.0f) + log1pf(expf(-fabsf(x)));  // jax softplus
        out[(long)VNUM * DIM + v * DIM + lane] = sp + EPS;
    }
}

extern "C" void kernel_launch(void* const* d_in, const int* in_sizes, int n_in,
                              void* d_out, int out_size, void* d_ws, size_t ws_size,
                              hipStream_t stream) {
    const int*   eidx  = (const int*)d_in[0];
    const float* enorm = (const float*)d_in[1];
    const float* esgn  = (const float*)d_in[2];
    const float* vrepr = (const float*)d_in[3];
    const float* W_loc = (const float*)d_in[4];
    const float* b_loc = (const float*)d_in[5];
    const float* W_std = (const float*)d_in[6];
    const float* b_std = (const float*)d_in[7];
    float* out = (float*)d_out;

    unsigned* cnt     = (unsigned*)d_ws;
    unsigned* ovf_cnt = (unsigned*)((char*)d_ws + 262144);
    uint2*    bucket  = (uint2*)((char*)d_ws + (1 << 20));
    unsigned* ovf     = (unsigned*)((char*)d_ws + (1 << 20) +
                                    (size_t)NBIN * NREP * SUBCAP * sizeof(uint2));

    // zero padded counters + overflow count
    hipMemsetAsync(d_ws, 0, 524288, stream);

    // one pass: bucket edges by target bin
    bucket_kernel<<<(NEDGE + 255) / 256, 256, 0, stream>>>(
        eidx, enorm, esgn, cnt, ovf_cnt, bucket, ovf);

    // one block per bin: accumulate (8-deep MLP) + fused heads
    accum_head_kernel<<<NBIN, 1024, 0, stream>>>(
        vrepr, W_loc, b_loc, W_std, b_std, cnt, ovf_cnt, bucket, ovf, out);
}